// Round 11
// baseline (711.564 us; speedup 1.0000x reference)
//
#include <hip/hip_runtime.h>

#define N_NODES   50000
#define N_EDGES   600000
#define IN_CH     300
#define HID       128
#define N_CLASSES 2
#define N_GRAPHS  128
#define BN_EPS    1e-5f

#define NB ((N_NODES + 511) / 512)   // scan blocks = 98
#define KP1 320
#define NREP 32                      // replicated BN-stat accumulators
#define DEGB ((N_EDGES + 255) / 256) // 2344
#define GEMMX_BLOCKS ((N_NODES + 63) / 64)   // 782
#define FILLB ((N_EDGES + 255) / 256)        // 2344
#define GATB (N_NODES / 16)                  // 3125 gather blocks (16 nodes each)

typedef __attribute__((ext_vector_type(8))) short bf8_t;   // 8 bf16 (4 VGPRs)
typedef __attribute__((ext_vector_type(4))) float f4_t;    // MFMA acc

// bf16 round-to-nearest-even helpers
__device__ __forceinline__ unsigned short f2bf(float x) {
    union { float f; unsigned u; } q; q.f = x;
    unsigned r = q.u + 0x7fffu + ((q.u >> 16) & 1u);
    return (unsigned short)(r >> 16);
}
__device__ __forceinline__ float bf2f(unsigned short h) {
    union { float f; unsigned u; } q; q.u = ((unsigned)h) << 16; return q.f;
}

// ---------------------------------------------------------------------------
// combined: degree count (blocks 0..DEGB-1) + weight prep (blocks DEGB..)
// B written in MFMA FRAGMENT order (see R2).
// ---------------------------------------------------------------------------
__global__ __launch_bounds__(256) void deg_prepw(const int* __restrict__ dst,
                                                 int* __restrict__ ideg,
                                                 const float* __restrict__ W1l,
                                                 const float* __restrict__ W1r,
                                                 const float* __restrict__ W2l,
                                                 const float* __restrict__ W2r,
                                                 const float* __restrict__ W3l,
                                                 const float* __restrict__ W3r,
                                                 unsigned short* __restrict__ B1h,
                                                 unsigned short* __restrict__ B1l,
                                                 unsigned short* __restrict__ B2h,
                                                 unsigned short* __restrict__ B2l,
                                                 unsigned short* __restrict__ B3h,
                                                 unsigned short* __restrict__ B3l) {
    int b = blockIdx.x;
    if (b < DEGB) {
        int e = b * 256 + threadIdx.x;
        if (e < N_EDGES) atomicAdd(&ideg[dst[e]], 1);
        return;
    }
    int pb = b - DEGB;
    int layer, base;
    if (pb < 320)      { layer = 0; base = pb; }
    else if (pb < 448) { layer = 1; base = pb - 320; }
    else               { layer = 2; base = pb - 448; }
    int Kp = (layer == 0) ? KP1 : HID;
    int K  = (layer == 0) ? IN_CH : HID;
    const float* Wl = (layer == 0) ? W1l : ((layer == 1) ? W2l : W3l);
    const float* Wr = (layer == 0) ? W1r : ((layer == 1) ? W2r : W3r);
    unsigned short* Bh = (layer == 0) ? B1h : ((layer == 1) ? B2h : B3h);
    unsigned short* Bl = (layer == 0) ? B1l : ((layer == 1) ? B2l : B3l);
    int idx = base * 256 + threadIdx.x;     // grid sized exactly: 256*Kp/256 blocks
    int n = idx / Kp;
    int k = idx - n * Kp;
    float v = 0.f;
    if (k < K) v = (n < 128) ? Wl[k * 128 + n] : Wr[k * 128 + (n - 128)];
    unsigned short h = f2bf(v);
    unsigned short l = f2bf(v - bf2f(h));
    int NST   = Kp >> 5;
    int ntile = n >> 4;
    int l16n  = n & 15;
    int kstep = k >> 5;
    int kk    = k & 31;
    int lane2 = (kk >> 3) * 16 + l16n;
    int addr  = ((ntile * NST + kstep) * 64 + lane2) * 8 + (kk & 7);
    Bh[addr] = h;
    Bl[addr] = l;
}

// ---------------------------------------------------------------------------
// single-dispatch exclusive scan (decoupled lookback) + invdeg
// ---------------------------------------------------------------------------
__global__ __launch_bounds__(256) void scan_fused(const int* __restrict__ ideg,
                                                  int* __restrict__ row_start,
                                                  float* __restrict__ invdeg,
                                                  int* __restrict__ bsum,
                                                  int* __restrict__ bflag) {
    int b = blockIdx.x, t = threadIdx.x;
    int lane = t & 63, wv = t >> 6;
    int i0 = b * 512 + t * 2;
    int v0 = 0, v1 = 0;
    if (i0 < N_NODES) {
        int2 v = *(const int2*)&ideg[i0];
        v0 = v.x; v1 = v.y;
    }
    int tot = v0 + v1;
    int s = tot;                              // inclusive wave scan
#pragma unroll
    for (int d = 1; d < 64; d <<= 1) {
        int u = __shfl_up(s, d);
        if (lane >= d) s += u;
    }
    __shared__ int ws[4];
    if (lane == 63) ws[wv] = s;
    __syncthreads();
    int btot = ws[0] + ws[1] + ws[2] + ws[3];
    if (t == 0) {                             // publish early
        atomicExch(&bsum[b], btot);
        __threadfence();
        atomicExch(&bflag[b], 1);
    }
    int part = 0;
    if (t < b) {
        while (atomicAdd(&bflag[t], 0) == 0) {}
        part = atomicAdd(&bsum[t], 0);
    }
#pragma unroll
    for (int d = 1; d < 64; d <<= 1) part += __shfl_down(part, d);
    __shared__ int ps[4];
    if (lane == 0) ps[wv] = part;
    __syncthreads();
    int boff = ps[0] + ps[1] + ps[2] + ps[3];
    int woff = 0;
    for (int w = 0; w < wv; ++w) woff += ws[w];
    int base = boff + woff + (s - tot);       // exclusive prefix for i0
    if (i0 < N_NODES) {
        row_start[i0]     = base;
        row_start[i0 + 1] = base + v0;
        invdeg[i0]     = 1.0f / fmaxf((float)v0, 1.0f);
        invdeg[i0 + 1] = 1.0f / fmaxf((float)v1, 1.0f);
    }
    if (t == 0 && b == NB - 1) row_start[N_NODES] = boff + btot;
}

// ---------------------------------------------------------------------------
// layer-1 GEMM (R6 config) MERGED with CSR fill (R10, verified 73us).
// ---------------------------------------------------------------------------
__global__ __launch_bounds__(256) void gemm_x_fill(const float* __restrict__ X,
                                                   int M,
                                                   const unsigned short* __restrict__ Bhi,
                                                   const unsigned short* __restrict__ Blo,
                                                   const float* __restrict__ bias,
                                                   unsigned short* __restrict__ C0,
                                                   float* __restrict__ C1,
                                                   const int* __restrict__ esrc,
                                                   const int* __restrict__ edst,
                                                   const int* __restrict__ row_start,
                                                   int* __restrict__ cursor,
                                                   int* __restrict__ csr_src) {
    if (blockIdx.x >= GEMMX_BLOCKS) {
        int e = (blockIdx.x - GEMMX_BLOCKS) * 256 + threadIdx.x;
        if (e < N_EDGES) {
            int d = edst[e];
            int pos = row_start[d] + atomicAdd(&cursor[d], 1);
            csr_src[pos] = esrc[e];
        }
        return;
    }

    __shared__ __align__(16) unsigned short sAh[2][64 * 32];
    __shared__ __align__(16) unsigned short sAl[2][64 * 32];

    const int tid  = threadIdx.x;
    const int lane = tid & 63;
    const int wave = tid >> 6;
    const int l16  = lane & 15;
    const int quad = lane >> 4;
    const long m0  = (long)blockIdx.x * 64;
    const int  n0  = wave * 64;

    f4_t acc[4][4];
#pragma unroll
    for (int mt = 0; mt < 4; ++mt)
#pragma unroll
        for (int nt = 0; nt < 4; ++nt) acc[mt][nt] = (f4_t){0.f, 0.f, 0.f, 0.f};

    const int ar  = tid >> 2;
    const int cl  = tid & 3;
    const int cpa = cl ^ ((ar >> 1) & 3);      // physical chunk (swizzle)
    long agr = m0 + ar;
    if (agr >= M) agr = M - 1;
    const float* gX = X + agr * IN_CH;

    const int rsw = (quad ^ ((l16 >> 1) & 3)) * 8;
    const int NT  = KP1 / 32;                  // 10

    const bf8_t* Bh0 = (const bf8_t*)Bhi;      // frag idx = (ntile*NT + t)*64 + lane
    const bf8_t* Bl0 = (const bf8_t*)Blo;

    auto loadA = [&](int k0, float4& a0, float4& a1) {
        int gk = k0 + cl * 8;
        a0 = (gk + 4 <= IN_CH) ? *(const float4*)(gX + gk)
                               : make_float4(0.f, 0.f, 0.f, 0.f);
        a1 = (gk + 8 <= IN_CH) ? *(const float4*)(gX + gk + 4)
                               : make_float4(0.f, 0.f, 0.f, 0.f);
    };
    auto storeA = [&](int buf, float4 a0, float4 a1) {
        float f[8];
        f[0] = a0.x; f[1] = a0.y; f[2] = a0.z; f[3] = a0.w;
        f[4] = a1.x; f[5] = a1.y; f[6] = a1.z; f[7] = a1.w;
        bf8_t h8, l8;
#pragma unroll
        for (int j = 0; j < 8; ++j) {
            unsigned short h = f2bf(f[j]);
            h8[j] = (short)h;
            l8[j] = (short)f2bf(f[j] - bf2f(h));
        }
        *(bf8_t*)&sAh[buf][ar * 32 + cpa * 8] = h8;
        *(bf8_t*)&sAl[buf][ar * 32 + cpa * 8] = l8;
    };
    auto loadB = [&](int t, bf8_t (&bh)[4], bf8_t (&bl)[4]) {
#pragma unroll
        for (int nt = 0; nt < 4; ++nt) {
            long bi = ((long)(wave * 4 + nt) * NT + t) * 64 + lane;
            bh[nt] = Bh0[bi];
            bl[nt] = Bl0[bi];
        }
    };

    // prologue: stage A step 0, prefetch B step 0
    bf8_t bhv[4], blv[4];
    {
        float4 a0, a1;
        loadA(0, a0, a1);
        loadB(0, bhv, blv);
        storeA(0, a0, a1);
    }
    __syncthreads();

    int cur = 0;
    for (int t = 0; t < NT; ++t) {
        float4 na0 = make_float4(0.f, 0.f, 0.f, 0.f);
        float4 na1 = make_float4(0.f, 0.f, 0.f, 0.f);
        bf8_t nbh[4], nbl[4];
        const bool more = (t + 1 < NT);
        if (more) {
            loadA((t + 1) * 32, na0, na1);     // in flight across MFMA cluster
            loadB(t + 1, nbh, nbl);            // B(t+1) latency hidden by MFMAs
        }

        bf8_t ah[4], al[4];
#pragma unroll
        for (int mt = 0; mt < 4; ++mt) {
            ah[mt] = *(const bf8_t*)&sAh[cur][(mt * 16 + l16) * 32 + rsw];
            al[mt] = *(const bf8_t*)&sAl[cur][(mt * 16 + l16) * 32 + rsw];
        }
        // 3 passes of 16 independent MFMAs (per-acc order hh->lh->hl preserved)
#pragma unroll
        for (int nt = 0; nt < 4; ++nt)
#pragma unroll
            for (int mt = 0; mt < 4; ++mt)
                acc[mt][nt] = __builtin_amdgcn_mfma_f32_16x16x32_bf16(ah[mt], bhv[nt], acc[mt][nt], 0, 0, 0);
#pragma unroll
        for (int nt = 0; nt < 4; ++nt)
#pragma unroll
            for (int mt = 0; mt < 4; ++mt)
                acc[mt][nt] = __builtin_amdgcn_mfma_f32_16x16x32_bf16(al[mt], bhv[nt], acc[mt][nt], 0, 0, 0);
#pragma unroll
        for (int nt = 0; nt < 4; ++nt)
#pragma unroll
            for (int mt = 0; mt < 4; ++mt)
                acc[mt][nt] = __builtin_amdgcn_mfma_f32_16x16x32_bf16(ah[mt], blv[nt], acc[mt][nt], 0, 0, 0);

        if (more) {
            storeA(cur ^ 1, na0, na1);         // consume A loads; vmcnt drains here
#pragma unroll
            for (int nt = 0; nt < 4; ++nt) {   // rotate prefetched B
                bhv[nt] = nbh[nt];
                blv[nt] = nbl[nt];
            }
        }
        __syncthreads();
        cur ^= 1;
    }

    const bool left = (n0 < 128);
    if (left) {
        int ncol[4];
#pragma unroll
        for (int nt = 0; nt < 4; ++nt) ncol[nt] = n0 + nt * 16 + l16;
#pragma unroll
        for (int mt = 0; mt < 4; ++mt)
#pragma unroll
            for (int r = 0; r < 4; ++r) {
                long row = m0 + mt * 16 + quad * 4 + r;
                if (row < M) {
#pragma unroll
                    for (int nt = 0; nt < 4; ++nt)
                        C0[row * 128 + ncol[nt]] = f2bf(acc[mt][nt][r]);
                }
            }
    } else {
        float badd[4];
        int   ncol[4];
#pragma unroll
        for (int nt = 0; nt < 4; ++nt) {
            int ng = n0 + nt * 16 + l16 - 128;
            ncol[nt] = ng;
            badd[nt] = bias[ng];
        }
#pragma unroll
        for (int mt = 0; mt < 4; ++mt)
#pragma unroll
            for (int r = 0; r < 4; ++r) {
                long row = m0 + mt * 16 + quad * 4 + r;
                if (row < M) {
#pragma unroll
                    for (int nt = 0; nt < 4; ++nt)
                        C1[row * 128 + ncol[nt]] = acc[mt][nt][r] + badd[nt];
                }
            }
    }
}

// ---------------------------------------------------------------------------
// layers 2/3 GEMM with FUSED BatchNorm+ReLU on A (R6 K-loop), R11: BN
// scale/shift read from precomputed SCg (written by the previous gather's
// last block) -> no per-block rep reduction, one fewer barrier.
// ---------------------------------------------------------------------------
__global__ __launch_bounds__(256) void gemm_mfma_h(const float* __restrict__ Hpre,
                                                   int M,
                                                   const float* __restrict__ SCg,
                                                   const unsigned short* __restrict__ Bhi,
                                                   const unsigned short* __restrict__ Blo,
                                                   const float* __restrict__ bias,
                                                   unsigned short* __restrict__ C0,
                                                   float* __restrict__ C1) {
    __shared__ __align__(16) unsigned short sAh[2][64 * 32];
    __shared__ __align__(16) unsigned short sAl[2][64 * 32];
    __shared__ float sSC[256];   // [scale 128 | shift 128]

    const int tid  = threadIdx.x;
    const int lane = tid & 63;
    const int wave = tid >> 6;
    const int l16  = lane & 15;
    const int quad = lane >> 4;
    const long m0  = (long)blockIdx.x * 64;
    const int  n0  = wave * 64;

    sSC[tid] = SCg[tid];                      // 1KB, L2-hot

    f4_t acc[4][4];
#pragma unroll
    for (int mt = 0; mt < 4; ++mt)
#pragma unroll
        for (int nt = 0; nt < 4; ++nt) acc[mt][nt] = (f4_t){0.f, 0.f, 0.f, 0.f};

    const int ar  = tid >> 2;
    const int cl  = tid & 3;
    const int cpa = cl ^ ((ar >> 1) & 3);
    long agr = m0 + ar;
    if (agr >= M) agr = M - 1;
    const float* gH = Hpre + agr * HID;

    const int rsw = (quad ^ ((l16 >> 1) & 3)) * 8;
    const int NT  = HID / 32;                  // 4

    const bf8_t* Bh0 = (const bf8_t*)Bhi;
    const bf8_t* Bl0 = (const bf8_t*)Blo;

    auto loadA = [&](int k0, float4& a0, float4& a1) {
        int gk = k0 + cl * 8;
        a0 = *(const float4*)(gH + gk);
        a1 = *(const float4*)(gH + gk + 4);
    };
    auto storeA = [&](int buf, int k0, float4 v0, float4 v1) {
        const int gk = k0 + cl * 8;
        float4 s0 = *(const float4*)&sSC[gk];
        float4 s1 = *(const float4*)&sSC[gk + 4];
        float4 t0 = *(const float4*)&sSC[HID + gk];
        float4 t1 = *(const float4*)&sSC[HID + gk + 4];
        float f[8];
        f[0] = fmaxf(v0.x * s0.x + t0.x, 0.f);
        f[1] = fmaxf(v0.y * s0.y + t0.y, 0.f);
        f[2] = fmaxf(v0.z * s0.z + t0.z, 0.f);
        f[3] = fmaxf(v0.w * s0.w + t0.w, 0.f);
        f[4] = fmaxf(v1.x * s1.x + t1.x, 0.f);
        f[5] = fmaxf(v1.y * s1.y + t1.y, 0.f);
        f[6] = fmaxf(v1.z * s1.z + t1.z, 0.f);
        f[7] = fmaxf(v1.w * s1.w + t1.w, 0.f);
        bf8_t h8, l8;
#pragma unroll
        for (int j = 0; j < 8; ++j) {
            unsigned short h = f2bf(f[j]);
            h8[j] = (short)h;
            l8[j] = (short)f2bf(f[j] - bf2f(h));
        }
        *(bf8_t*)&sAh[buf][ar * 32 + cpa * 8] = h8;
        *(bf8_t*)&sAl[buf][ar * 32 + cpa * 8] = l8;
    };
    auto loadB = [&](int t, bf8_t (&bh)[4], bf8_t (&bl)[4]) {
#pragma unroll
        for (int nt = 0; nt < 4; ++nt) {
            long bi = ((long)(wave * 4 + nt) * NT + t) * 64 + lane;
            bh[nt] = Bh0[bi];
            bl[nt] = Bl0[bi];
        }
    };

    // prologue: load A(0)+B(0); barrier so sSC is visible; stage A(0)
    bf8_t bhv[4], blv[4];
    {
        float4 a0, a1;
        loadA(0, a0, a1);
        loadB(0, bhv, blv);
        __syncthreads();                       // sSC ready
        storeA(0, 0, a0, a1);
    }
    __syncthreads();

    int cur = 0;
#pragma unroll
    for (int t = 0; t < 4; ++t) {              // HID/32 = 4 steps
        float4 na0 = make_float4(0.f, 0.f, 0.f, 0.f);
        float4 na1 = make_float4(0.f, 0.f, 0.f, 0.f);
        bf8_t nbh[4], nbl[4];
        const bool more = (t < 3);
        if (more) {
            loadA((t + 1) * 32, na0, na1);
            loadB(t + 1, nbh, nbl);
        }

        bf8_t ah[4], al[4];
#pragma unroll
        for (int mt = 0; mt < 4; ++mt) {
            ah[mt] = *(const bf8_t*)&sAh[cur][(mt * 16 + l16) * 32 + rsw];
            al[mt] = *(const bf8_t*)&sAl[cur][(mt * 16 + l16) * 32 + rsw];
        }
#pragma unroll
        for (int nt = 0; nt < 4; ++nt)
#pragma unroll
            for (int mt = 0; mt < 4; ++mt)
                acc[mt][nt] = __builtin_amdgcn_mfma_f32_16x16x32_bf16(ah[mt], bhv[nt], acc[mt][nt], 0, 0, 0);
#pragma unroll
        for (int nt = 0; nt < 4; ++nt)
#pragma unroll
            for (int mt = 0; mt < 4; ++mt)
                acc[mt][nt] = __builtin_amdgcn_mfma_f32_16x16x32_bf16(al[mt], bhv[nt], acc[mt][nt], 0, 0, 0);
#pragma unroll
        for (int nt = 0; nt < 4; ++nt)
#pragma unroll
            for (int mt = 0; mt < 4; ++mt)
                acc[mt][nt] = __builtin_amdgcn_mfma_f32_16x16x32_bf16(ah[mt], blv[nt], acc[mt][nt], 0, 0, 0);

        if (more) {
            storeA(cur ^ 1, (t + 1) * 32, na0, na1);
#pragma unroll
            for (int nt = 0; nt < 4; ++nt) {
                bhv[nt] = nbh[nt];
                blv[nt] = nbl[nt];
            }
        }
        __syncthreads();
        cur ^= 1;
    }

    const bool left = (n0 < 128);
    if (left) {
        int ncol[4];
#pragma unroll
        for (int nt = 0; nt < 4; ++nt) ncol[nt] = n0 + nt * 16 + l16;
#pragma unroll
        for (int mt = 0; mt < 4; ++mt)
#pragma unroll
            for (int r = 0; r < 4; ++r) {
                long row = m0 + mt * 16 + quad * 4 + r;
                if (row < M) {
#pragma unroll
                    for (int nt = 0; nt < 4; ++nt)
                        C0[row * 128 + ncol[nt]] = f2bf(acc[mt][nt][r]);
                }
            }
    } else {
        float badd[4];
        int   ncol[4];
#pragma unroll
        for (int nt = 0; nt < 4; ++nt) {
            int ng = n0 + nt * 16 + l16 - 128;
            ncol[nt] = ng;
            badd[nt] = bias[ng];
        }
#pragma unroll
        for (int mt = 0; mt < 4; ++mt)
#pragma unroll
            for (int r = 0; r < 4; ++r) {
                long row = m0 + mt * 16 + quad * 4 + r;
                if (row < M) {
#pragma unroll
                    for (int nt = 0; nt < 4; ++nt)
                        C1[row * 128 + ncol[nt]] = acc[mt][nt][r] + badd[nt];
                }
            }
    }
}

// ---------------------------------------------------------------------------
// CSR gather + BN-stat tail, R11: 16 nodes/block, 16 lanes/node, bf8_t
// (16B) loads — halves load instrs and block rounds.  16-edge first flight.
// LAST block (device counter) computes BN scale/shift into SCg — removes
// the rep-reduction preamble from gemm_h/poolhead with no extra dispatch.
// Per-channel accumulation order unchanged -> node outputs bit-identical.
// ---------------------------------------------------------------------------
__global__ __launch_bounds__(256) void gather_agg(const unsigned short* __restrict__ Pl,
                                                  const int* __restrict__ row_start,
                                                  const int* __restrict__ csr_src,
                                                  const float* __restrict__ invdeg,
                                                  float* __restrict__ out,
                                                  float* __restrict__ rep,
                                                  const float* __restrict__ gamma,
                                                  const float* __restrict__ beta,
                                                  float* __restrict__ SCg,
                                                  int* __restrict__ dcnt) {
    int slot = threadIdx.x >> 4;               // 0..15
    int lane = threadIdx.x & 15;               // 0..15
    int node = blockIdx.x * 16 + slot;         // grid exact: 3125*16 = 50000
    int beg = row_start[node];
    int end = row_start[node + 1];
    const unsigned short* base = Pl + lane * 8;
    float s[8];
#pragma unroll
    for (int i = 0; i < 8; ++i) s[i] = 0.f;
    int j = beg;
    int deg = end - beg;

    // ---- first round: up to 16 edges, all loads in one flight ----
    if (deg > 0) {
        int n16 = (deg < 16) ? deg : 16;
        int idx[16];
#pragma unroll
        for (int u = 0; u < 16; ++u)
            idx[u] = csr_src[(u < n16) ? (j + u) : j];      // clamped: safe addr
        bf8_t v[16];
#pragma unroll
        for (int u = 0; u < 16; ++u)
            v[u] = *(const bf8_t*)(base + (long)idx[u] * HID);
#pragma unroll
        for (int u = 0; u < 16; ++u) {
            float m = (u < n16) ? 1.f : 0.f;                // +0.f is exact
#pragma unroll
            for (int i = 0; i < 8; ++i)
                s[i] += m * bf2f((unsigned short)v[u][i]);
        }
        j += n16;
    }
    // ---- continuation for deg > 16 (rare) ----
    for (; j + 8 <= end; j += 8) {
        int idx[8];
#pragma unroll
        for (int u = 0; u < 8; ++u) idx[u] = csr_src[j + u];
        bf8_t v[8];
#pragma unroll
        for (int u = 0; u < 8; ++u) v[u] = *(const bf8_t*)(base + (long)idx[u] * HID);
#pragma unroll
        for (int u = 0; u < 8; ++u)
#pragma unroll
            for (int i = 0; i < 8; ++i)
                s[i] += bf2f((unsigned short)v[u][i]);
    }
    for (; j < end; ++j) {
        int i0 = csr_src[j];
        bf8_t v0 = *(const bf8_t*)(base + (long)i0 * HID);
#pragma unroll
        for (int i = 0; i < 8; ++i) s[i] += bf2f((unsigned short)v0[i]);
    }
    float w = invdeg[node];
    float* o = out + (long)node * HID + lane * 8;
    float4 c0 = *(float4*)o;
    float4 c1 = *(float4*)(o + 4);
    c0.x += s[0] * w; c0.y += s[1] * w; c0.z += s[2] * w; c0.w += s[3] * w;
    c1.x += s[4] * w; c1.y += s[5] * w; c1.z += s[6] * w; c1.w += s[7] * w;
    *(float4*)o       = c0;
    *(float4*)(o + 4) = c1;

    // ---- BN stats tail: one LDS round, sum + sumsq together ----
    __shared__ float red[16][HID];             // 8KB
    float* repb = rep + (blockIdx.x & (NREP - 1)) * 256;
    *(float4*)&red[slot][lane * 8]     = c0;
    *(float4*)&red[slot][lane * 8 + 4] = c1;
    __syncthreads();
    if (threadIdx.x < HID) {
        float tsum = 0.f, tsq = 0.f;
#pragma unroll
        for (int ss = 0; ss < 16; ++ss) {
            float v = red[ss][threadIdx.x];
            tsum += v;
            tsq  += v * v;
        }
        atomicAdd(&repb[threadIdx.x], tsum);
        atomicAdd(&repb[HID + threadIdx.x], tsq);
    }

    // ---- LAST block computes BN scale/shift (no extra dispatch) ----
    __syncthreads();                           // drain this block's atomics
    __shared__ int isLast;
    if (threadIdx.x == 0) {
        __threadfence();                       // adds visible device-wide
        int d = atomicAdd(dcnt, 1);
        isLast = (d == GATB - 1);
    }
    __syncthreads();
    if (isLast) {
        int t = threadIdx.x;
        volatile const float* vrep = rep;      // sc0 loads: bypass L1
        float a = 0.f;
#pragma unroll
        for (int r = 0; r < NREP; ++r) a += vrep[r * 256 + t];
        __shared__ float S[256];
        S[t] = a;
        __syncthreads();
        if (t < HID) {
            const float invn = 1.0f / (float)N_NODES;
            float mu  = S[t] * invn;
            float var = S[HID + t] * invn - mu * mu;
            float sc  = gamma[t] * rsqrtf(var + BN_EPS);
            SCg[t]       = sc;
            SCg[HID + t] = beta[t] - mu * sc;
        }
    }
}

// ---------------------------------------------------------------------------
// fused BN+ReLU + mean-pool + head: one block/graph, 1024 thr.
// R11: BN scale/shift from precomputed SCg (no per-block reduction).
// out = [logits(128x2) | hg(128x128)]
// ---------------------------------------------------------------------------
__global__ __launch_bounds__(1024) void poolhead_bn(const float* __restrict__ h,
                                                    const int* __restrict__ batch,
                                                    const float* __restrict__ SCg,
                                                    const float* __restrict__ Wc,
                                                    const float* __restrict__ bc,
                                                    float* __restrict__ out) {
    __shared__ float SC[256];
    int g = blockIdx.x;
    int t = threadIdx.x;
    int c = t & 127;
    int half = t >> 7;                 // 0..7
    if (t < 256) SC[t] = SCg[t];
    __shared__ int lo_sh, hi_sh;
    if (t == 0) {
        int lo = 0, hi = N_NODES;
        while (lo < hi) { int m = (lo + hi) >> 1; if (batch[m] < g) lo = m + 1; else hi = m; }
        lo_sh = lo;
        int lo2 = lo, hi2 = N_NODES;
        while (lo2 < hi2) { int m = (lo2 + hi2) >> 1; if (batch[m] < g + 1) lo2 = m + 1; else hi2 = m; }
        hi_sh = lo2;
    }
    __syncthreads();
    float bsc = SC[c], bsh = SC[HID + c];
    int lo = lo_sh, hi = hi_sh;
    float a0 = 0.f, a1 = 0.f, a2 = 0.f, a3 = 0.f;
    int r = lo + half;
    for (; r + 24 < hi; r += 32) {     // 4 independent loads in flight
        a0 += fmaxf(h[(long)(r +  0) * HID + c] * bsc + bsh, 0.f);
        a1 += fmaxf(h[(long)(r +  8) * HID + c] * bsc + bsh, 0.f);
        a2 += fmaxf(h[(long)(r + 16) * HID + c] * bsc + bsh, 0.f);
        a3 += fmaxf(h[(long)(r + 24) * HID + c] * bsc + bsh, 0.f);
    }
    for (; r < hi; r += 8) a0 += fmaxf(h[(long)r * HID + c] * bsc + bsh, 0.f);
    __shared__ float red[8][HID];
    red[half][c] = (a0 + a1) + (a2 + a3);
    __syncthreads();
    __shared__ float r0[HID], r1[HID];
    if (t < HID) {
        float inv = 1.0f / fmaxf((float)(hi - lo), 1.0f);
        float v = 0.f;
#pragma unroll
        for (int s = 0; s < 8; ++s) v += red[s][t];
        v *= inv;
        out[N_GRAPHS * N_CLASSES + g * HID + t] = v;   // hg
        r0[t] = v * Wc[t * 2 + 0];
        r1[t] = v * Wc[t * 2 + 1];
    }
    __syncthreads();
    if (t < 2) {
        const float* rr = t ? r1 : r0;
        float sum = bc[t];
        for (int i = 0; i < HID; ++i) sum += rr[i];
        out[g * 2 + t] = sum;
    }
}

// ---------------------------------------------------------------------------
// launch
// ---------------------------------------------------------------------------
extern "C" void kernel_launch(void* const* d_in, const int* in_sizes, int n_in,
                              void* d_out, int out_size, void* d_ws, size_t ws_size,
                              hipStream_t stream) {
    const float* x     = (const float*)d_in[0];
    const int*   ei    = (const int*)d_in[1];
    const int*   batch = (const int*)d_in[2];
    const float* W1l = (const float*)d_in[3];
    const float* W1r = (const float*)d_in[4];
    const float* b1  = (const float*)d_in[5];
    const float* g1  = (const float*)d_in[6];
    const float* be1 = (const float*)d_in[7];
    const float* W2l = (const float*)d_in[8];
    const float* W2r = (const float*)d_in[9];
    const float* b2  = (const float*)d_in[10];
    const float* g2  = (const float*)d_in[11];
    const float* be2 = (const float*)d_in[12];
    const float* W3l = (const float*)d_in[13];
    const float* W3r = (const float*)d_in[14];
    const float* b3  = (const float*)d_in[15];
    const float* g3  = (const float*)d_in[16];
    const float* be3 = (const float*)d_in[17];
    const float* Wc  = (const float*)d_in[18];
    const float* bc  = (const float*)d_in[19];

    const int* src = ei;
    const int* dst = ei + N_EDGES;

    float* ws = (float*)d_ws;
    const long FEAT = (long)N_NODES * HID;
    unsigned short* Pl16 = (unsigned short*)ws;      // FEAT ushorts
    float* buf1 = ws + FEAT;                         // layer 1&3 pre-BN h (fp32)
    float* buf2 = ws + 2 * FEAT;                     // layer 2 pre-BN h (fp32)
    int*   ideg      = (int*)(ws + 3 * FEAT);        // 50000
    int*   cursor    = ideg + N_NODES;               // 50000
    int*   bsum      = cursor + N_NODES;             // 128
    int*   bflag     = bsum + 128;                   // 128
    int*   row_start = bflag + 128;                  // 50001 (pad 50004)
    int*   csr_src   = row_start + N_NODES + 4;      // 600000
    float* invdeg    = (float*)(csr_src + N_EDGES);  // 50000
    float* reps      = invdeg + N_NODES;             // 3*32*256 = 24576
    float* SC1g      = reps + 3 * NREP * 256;        // 256
    float* SC2g      = SC1g + 256;                   // 256
    float* SC3g      = SC2g + 256;                   // 256
    int*   dcnt      = (int*)(SC3g + 256);           // 4 ints
    unsigned short* B1h = (unsigned short*)(dcnt + 4);               // 256*320
    unsigned short* B1l = B1h + 256 * KP1;
    unsigned short* B2h = B1l + 256 * KP1;                           // 256*128
    unsigned short* B2l = B2h + 256 * HID;
    unsigned short* B3h = B2l + 256 * HID;
    unsigned short* B3l = B3h + 256 * HID;

    float* outp = (float*)d_out;

    const int gemm_grid   = (N_NODES + 63) / 64;     // 782
    const int gxf_grid    = GEMMX_BLOCKS + FILLB;    // 3126
    const int dp_grid     = DEGB + 320 + 128 + 128;  // 2920

    // --- zero scratch (2 memsets; second covers reps + SC + dcnt) ---
    hipMemsetAsync(ideg, 0, (2 * N_NODES + 256) * sizeof(int), stream);
    hipMemsetAsync(reps, 0, (3 * NREP * 256 + 3 * 256 + 4) * sizeof(float), stream);

    // --- degree + weight prep (merged), then scan ---
    deg_prepw<<<dp_grid, 256, 0, stream>>>(dst, ideg, W1l, W1r, W2l, W2r, W3l, W3r,
                                           B1h, B1l, B2h, B2l, B3h, B3l);
    scan_fused<<<NB, 256, 0, stream>>>(ideg, row_start, invdeg, bsum, bflag);

    // ---------------- layer 1 GEMM + CSR fill (merged dispatch) ----------------
    gemm_x_fill<<<gxf_grid, 256, 0, stream>>>(x, N_NODES, B1h, B1l, b1, Pl16, buf1,
                                              src, dst, row_start, cursor, csr_src);
    gather_agg<<<GATB, 256, 0, stream>>>(Pl16, row_start, csr_src, invdeg, buf1, reps,
                                         g1, be1, SC1g, dcnt + 0);

    // ---------------- layer 2 (BN1 via SC1g, fused into A-staging) ----------------
    gemm_mfma_h<<<gemm_grid, 256, 0, stream>>>(buf1, N_NODES, SC1g,
                                               B2h, B2l, b2, Pl16, buf2);
    gather_agg<<<GATB, 256, 0, stream>>>(Pl16, row_start, csr_src, invdeg, buf2,
                                         reps + NREP * 256, g2, be2, SC2g, dcnt + 1);

    // ---------------- layer 3 (BN2 via SC2g, fused into A-staging) ----------------
    gemm_mfma_h<<<gemm_grid, 256, 0, stream>>>(buf2, N_NODES, SC2g,
                                               B3h, B3l, b3, Pl16, buf1);
    gather_agg<<<GATB, 256, 0, stream>>>(Pl16, row_start, csr_src, invdeg, buf1,
                                         reps + 2 * NREP * 256, g3, be3, SC3g, dcnt + 2);

    // ---------------- fused BN3 (via SC3g) + pool + head ----------------
    poolhead_bn<<<N_GRAPHS, 1024, 0, stream>>>(buf1, batch, SC3g, Wc, bc, outp);
}

// Round 12
// 356.233 us; speedup vs baseline: 1.9975x; 1.9975x over previous
//
#include <hip/hip_runtime.h>

#define N_NODES   50000
#define N_EDGES   600000
#define IN_CH     300
#define HID       128
#define N_CLASSES 2
#define N_GRAPHS  128
#define BN_EPS    1e-5f

#define NB ((N_NODES + 511) / 512)   // scan blocks = 98
#define KP1 320
#define NREP 32                      // replicated BN-stat accumulators
#define DEGB ((N_EDGES + 255) / 256) // 2344
#define GEMMX_BLOCKS ((N_NODES + 63) / 64)   // 782
#define FILLB ((N_EDGES + 255) / 256)        // 2344

typedef __attribute__((ext_vector_type(8))) short bf8_t;   // 8 bf16 (4 VGPRs)
typedef __attribute__((ext_vector_type(4))) float f4_t;    // MFMA acc

// bf16 round-to-nearest-even helpers
__device__ __forceinline__ unsigned short f2bf(float x) {
    union { float f; unsigned u; } q; q.f = x;
    unsigned r = q.u + 0x7fffu + ((q.u >> 16) & 1u);
    return (unsigned short)(r >> 16);
}
__device__ __forceinline__ float bf2f(unsigned short h) {
    union { float f; unsigned u; } q; q.u = ((unsigned)h) << 16; return q.f;
}

// ---------------------------------------------------------------------------
// combined: degree count (blocks 0..DEGB-1) + weight prep (blocks DEGB..)
// B written in MFMA FRAGMENT order (see R2): frag idx = ((ntile*NST + kstep)
// *64 + lane)*8 + j with lane = (kk>>3)*16 + (n&15), j = kk&7.
// ---------------------------------------------------------------------------
__global__ __launch_bounds__(256) void deg_prepw(const int* __restrict__ dst,
                                                 int* __restrict__ ideg,
                                                 const float* __restrict__ W1l,
                                                 const float* __restrict__ W1r,
                                                 const float* __restrict__ W2l,
                                                 const float* __restrict__ W2r,
                                                 const float* __restrict__ W3l,
                                                 const float* __restrict__ W3r,
                                                 unsigned short* __restrict__ B1h,
                                                 unsigned short* __restrict__ B1l,
                                                 unsigned short* __restrict__ B2h,
                                                 unsigned short* __restrict__ B2l,
                                                 unsigned short* __restrict__ B3h,
                                                 unsigned short* __restrict__ B3l) {
    int b = blockIdx.x;
    if (b < DEGB) {
        int e = b * 256 + threadIdx.x;
        if (e < N_EDGES) atomicAdd(&ideg[dst[e]], 1);
        return;
    }
    int pb = b - DEGB;
    int layer, base;
    if (pb < 320)      { layer = 0; base = pb; }
    else if (pb < 448) { layer = 1; base = pb - 320; }
    else               { layer = 2; base = pb - 448; }
    int Kp = (layer == 0) ? KP1 : HID;
    int K  = (layer == 0) ? IN_CH : HID;
    const float* Wl = (layer == 0) ? W1l : ((layer == 1) ? W2l : W3l);
    const float* Wr = (layer == 0) ? W1r : ((layer == 1) ? W2r : W3r);
    unsigned short* Bh = (layer == 0) ? B1h : ((layer == 1) ? B2h : B3h);
    unsigned short* Bl = (layer == 0) ? B1l : ((layer == 1) ? B2l : B3l);
    int idx = base * 256 + threadIdx.x;     // grid sized exactly: 256*Kp/256 blocks
    int n = idx / Kp;
    int k = idx - n * Kp;
    float v = 0.f;
    if (k < K) v = (n < 128) ? Wl[k * 128 + n] : Wr[k * 128 + (n - 128)];
    unsigned short h = f2bf(v);
    unsigned short l = f2bf(v - bf2f(h));
    // fragment-order address
    int NST   = Kp >> 5;
    int ntile = n >> 4;
    int l16n  = n & 15;
    int kstep = k >> 5;
    int kk    = k & 31;
    int lane2 = (kk >> 3) * 16 + l16n;
    int addr  = ((ntile * NST + kstep) * 64 + lane2) * 8 + (kk & 7);
    Bh[addr] = h;
    Bl[addr] = l;
}

// ---------------------------------------------------------------------------
// single-dispatch exclusive scan (decoupled lookback) + invdeg
// ---------------------------------------------------------------------------
__global__ __launch_bounds__(256) void scan_fused(const int* __restrict__ ideg,
                                                  int* __restrict__ row_start,
                                                  float* __restrict__ invdeg,
                                                  int* __restrict__ bsum,
                                                  int* __restrict__ bflag) {
    int b = blockIdx.x, t = threadIdx.x;
    int lane = t & 63, wv = t >> 6;
    int i0 = b * 512 + t * 2;
    int v0 = 0, v1 = 0;
    if (i0 < N_NODES) {
        int2 v = *(const int2*)&ideg[i0];
        v0 = v.x; v1 = v.y;
    }
    int tot = v0 + v1;
    int s = tot;                              // inclusive wave scan
#pragma unroll
    for (int d = 1; d < 64; d <<= 1) {
        int u = __shfl_up(s, d);
        if (lane >= d) s += u;
    }
    __shared__ int ws[4];
    if (lane == 63) ws[wv] = s;
    __syncthreads();
    int btot = ws[0] + ws[1] + ws[2] + ws[3];
    if (t == 0) {                             // publish early
        atomicExch(&bsum[b], btot);
        __threadfence();
        atomicExch(&bflag[b], 1);
    }
    int part = 0;
    if (t < b) {
        while (atomicAdd(&bflag[t], 0) == 0) {}
        part = atomicAdd(&bsum[t], 0);
    }
#pragma unroll
    for (int d = 1; d < 64; d <<= 1) part += __shfl_down(part, d);
    __shared__ int ps[4];
    if (lane == 0) ps[wv] = part;
    __syncthreads();
    int boff = ps[0] + ps[1] + ps[2] + ps[3];
    int woff = 0;
    for (int w = 0; w < wv; ++w) woff += ws[w];
    int base = boff + woff + (s - tot);       // exclusive prefix for i0
    if (i0 < N_NODES) {
        row_start[i0]     = base;
        row_start[i0 + 1] = base + v0;
        invdeg[i0]     = 1.0f / fmaxf((float)v0, 1.0f);
        invdeg[i0 + 1] = 1.0f / fmaxf((float)v1, 1.0f);
    }
    if (t == 0 && b == NB - 1) row_start[N_NODES] = boff + btot;
}

// ---------------------------------------------------------------------------
// layer-1 GEMM (R6 config, best measured: 46us) MERGED with CSR fill.
// Blocks [0, GEMMX_BLOCKS): 64x256 GEMM tile, 4 waves, B direct-global with
// 1-step register prefetch, A double-buffered in 16KB LDS, 1 barrier/K-step.
// Blocks [GEMMX_BLOCKS, +FILLB): CSR fill (independent work, co-scheduled
// into gemm's idle wave slots; removes one serial dispatch stage).
// ---------------------------------------------------------------------------
__global__ __launch_bounds__(256) void gemm_x_fill(const float* __restrict__ X,
                                                   int M,
                                                   const unsigned short* __restrict__ Bhi,
                                                   const unsigned short* __restrict__ Blo,
                                                   const float* __restrict__ bias,
                                                   unsigned short* __restrict__ C0,
                                                   float* __restrict__ C1,
                                                   const int* __restrict__ esrc,
                                                   const int* __restrict__ edst,
                                                   const int* __restrict__ row_start,
                                                   int* __restrict__ cursor,
                                                   int* __restrict__ csr_src) {
    if (blockIdx.x >= GEMMX_BLOCKS) {
        int e = (blockIdx.x - GEMMX_BLOCKS) * 256 + threadIdx.x;
        if (e < N_EDGES) {
            int d = edst[e];
            int pos = row_start[d] + atomicAdd(&cursor[d], 1);
            csr_src[pos] = esrc[e];
        }
        return;
    }

    __shared__ __align__(16) unsigned short sAh[2][64 * 32];
    __shared__ __align__(16) unsigned short sAl[2][64 * 32];

    const int tid  = threadIdx.x;
    const int lane = tid & 63;
    const int wave = tid >> 6;
    const int l16  = lane & 15;
    const int quad = lane >> 4;
    const long m0  = (long)blockIdx.x * 64;
    const int  n0  = wave * 64;

    f4_t acc[4][4];
#pragma unroll
    for (int mt = 0; mt < 4; ++mt)
#pragma unroll
        for (int nt = 0; nt < 4; ++nt) acc[mt][nt] = (f4_t){0.f, 0.f, 0.f, 0.f};

    const int ar  = tid >> 2;
    const int cl  = tid & 3;
    const int cpa = cl ^ ((ar >> 1) & 3);      // physical chunk (swizzle)
    long agr = m0 + ar;
    if (agr >= M) agr = M - 1;
    const float* gX = X + agr * IN_CH;

    const int rsw = (quad ^ ((l16 >> 1) & 3)) * 8;
    const int NT  = KP1 / 32;                  // 10

    const bf8_t* Bh0 = (const bf8_t*)Bhi;      // frag idx = (ntile*NT + t)*64 + lane
    const bf8_t* Bl0 = (const bf8_t*)Blo;

    auto loadA = [&](int k0, float4& a0, float4& a1) {
        int gk = k0 + cl * 8;
        a0 = (gk + 4 <= IN_CH) ? *(const float4*)(gX + gk)
                               : make_float4(0.f, 0.f, 0.f, 0.f);
        a1 = (gk + 8 <= IN_CH) ? *(const float4*)(gX + gk + 4)
                               : make_float4(0.f, 0.f, 0.f, 0.f);
    };
    auto storeA = [&](int buf, float4 a0, float4 a1) {
        float f[8];
        f[0] = a0.x; f[1] = a0.y; f[2] = a0.z; f[3] = a0.w;
        f[4] = a1.x; f[5] = a1.y; f[6] = a1.z; f[7] = a1.w;
        bf8_t h8, l8;
#pragma unroll
        for (int j = 0; j < 8; ++j) {
            unsigned short h = f2bf(f[j]);
            h8[j] = (short)h;
            l8[j] = (short)f2bf(f[j] - bf2f(h));
        }
        *(bf8_t*)&sAh[buf][ar * 32 + cpa * 8] = h8;
        *(bf8_t*)&sAl[buf][ar * 32 + cpa * 8] = l8;
    };
    auto loadB = [&](int t, bf8_t (&bh)[4], bf8_t (&bl)[4]) {
#pragma unroll
        for (int nt = 0; nt < 4; ++nt) {
            long bi = ((long)(wave * 4 + nt) * NT + t) * 64 + lane;
            bh[nt] = Bh0[bi];
            bl[nt] = Bl0[bi];
        }
    };

    // prologue: stage A step 0, prefetch B step 0
    bf8_t bhv[4], blv[4];
    {
        float4 a0, a1;
        loadA(0, a0, a1);
        loadB(0, bhv, blv);
        storeA(0, a0, a1);
    }
    __syncthreads();

    int cur = 0;
    for (int t = 0; t < NT; ++t) {
        float4 na0 = make_float4(0.f, 0.f, 0.f, 0.f);
        float4 na1 = make_float4(0.f, 0.f, 0.f, 0.f);
        bf8_t nbh[4], nbl[4];
        const bool more = (t + 1 < NT);
        if (more) {
            loadA((t + 1) * 32, na0, na1);     // in flight across MFMA cluster
            loadB(t + 1, nbh, nbl);            // B(t+1) latency hidden by MFMAs
        }

        bf8_t ah[4], al[4];
#pragma unroll
        for (int mt = 0; mt < 4; ++mt) {
            ah[mt] = *(const bf8_t*)&sAh[cur][(mt * 16 + l16) * 32 + rsw];
            al[mt] = *(const bf8_t*)&sAl[cur][(mt * 16 + l16) * 32 + rsw];
        }
        // 3 passes of 16 independent MFMAs (per-acc order hh->lh->hl preserved)
#pragma unroll
        for (int nt = 0; nt < 4; ++nt)
#pragma unroll
            for (int mt = 0; mt < 4; ++mt)
                acc[mt][nt] = __builtin_amdgcn_mfma_f32_16x16x32_bf16(ah[mt], bhv[nt], acc[mt][nt], 0, 0, 0);
#pragma unroll
        for (int nt = 0; nt < 4; ++nt)
#pragma unroll
            for (int mt = 0; mt < 4; ++mt)
                acc[mt][nt] = __builtin_amdgcn_mfma_f32_16x16x32_bf16(al[mt], bhv[nt], acc[mt][nt], 0, 0, 0);
#pragma unroll
        for (int nt = 0; nt < 4; ++nt)
#pragma unroll
            for (int mt = 0; mt < 4; ++mt)
                acc[mt][nt] = __builtin_amdgcn_mfma_f32_16x16x32_bf16(ah[mt], blv[nt], acc[mt][nt], 0, 0, 0);

        if (more) {
            storeA(cur ^ 1, na0, na1);         // consume A loads; vmcnt drains here
#pragma unroll
            for (int nt = 0; nt < 4; ++nt) {   // rotate prefetched B
                bhv[nt] = nbh[nt];
                blv[nt] = nbl[nt];
            }
        }
        __syncthreads();
        cur ^= 1;
    }

    const bool left = (n0 < 128);
    if (left) {
        int ncol[4];
#pragma unroll
        for (int nt = 0; nt < 4; ++nt) ncol[nt] = n0 + nt * 16 + l16;
#pragma unroll
        for (int mt = 0; mt < 4; ++mt)
#pragma unroll
            for (int r = 0; r < 4; ++r) {
                long row = m0 + mt * 16 + quad * 4 + r;
                if (row < M) {
#pragma unroll
                    for (int nt = 0; nt < 4; ++nt)
                        C0[row * 128 + ncol[nt]] = f2bf(acc[mt][nt][r]);
                }
            }
    } else {
        float badd[4];
        int   ncol[4];
#pragma unroll
        for (int nt = 0; nt < 4; ++nt) {
            int ng = n0 + nt * 16 + l16 - 128;
            ncol[nt] = ng;
            badd[nt] = bias[ng];
        }
#pragma unroll
        for (int mt = 0; mt < 4; ++mt)
#pragma unroll
            for (int r = 0; r < 4; ++r) {
                long row = m0 + mt * 16 + quad * 4 + r;
                if (row < M) {
#pragma unroll
                    for (int nt = 0; nt < 4; ++nt)
                        C1[row * 128 + ncol[nt]] = acc[mt][nt][r] + badd[nt];
                }
            }
    }
}

// ---------------------------------------------------------------------------
// layers 2/3 GEMM with FUSED BatchNorm+ReLU on the A operand (R6 config).
// ---------------------------------------------------------------------------
__global__ __launch_bounds__(256) void gemm_mfma_h(const float* __restrict__ Hpre,
                                                   int M,
                                                   const float* __restrict__ rep,
                                                   const float* __restrict__ gamma,
                                                   const float* __restrict__ beta,
                                                   const unsigned short* __restrict__ Bhi,
                                                   const unsigned short* __restrict__ Blo,
                                                   const float* __restrict__ bias,
                                                   unsigned short* __restrict__ C0,
                                                   float* __restrict__ C1) {
    __shared__ __align__(16) unsigned short sAh[2][64 * 32];
    __shared__ __align__(16) unsigned short sAl[2][64 * 32];
    __shared__ float sSC[256];   // [scale 128 | shift 128] — live through loop

    const int tid  = threadIdx.x;
    const int lane = tid & 63;
    const int wave = tid >> 6;
    const int l16  = lane & 15;
    const int quad = lane >> 4;
    const long m0  = (long)blockIdx.x * 64;
    const int  n0  = wave * 64;

    // ---- BN scale/shift preamble (S overlaid on sAh) ----
    {
        float* S = (float*)sAh;
        float a = 0.f;
#pragma unroll
        for (int r = 0; r < NREP; ++r) a += rep[r * 256 + tid];
        S[tid] = a;
        __syncthreads();
        if (tid < HID) {
            const float invn = 1.0f / (float)N_NODES;
            float mu  = S[tid] * invn;
            float var = S[HID + tid] * invn - mu * mu;
            float sc  = gamma[tid] * rsqrtf(var + BN_EPS);
            sSC[tid]       = sc;
            sSC[HID + tid] = beta[tid] - mu * sc;
        }
        __syncthreads();                       // S dead after this; sAh reusable
    }

    f4_t acc[4][4];
#pragma unroll
    for (int mt = 0; mt < 4; ++mt)
#pragma unroll
        for (int nt = 0; nt < 4; ++nt) acc[mt][nt] = (f4_t){0.f, 0.f, 0.f, 0.f};

    const int ar  = tid >> 2;
    const int cl  = tid & 3;
    const int cpa = cl ^ ((ar >> 1) & 3);
    long agr = m0 + ar;
    if (agr >= M) agr = M - 1;
    const float* gH = Hpre + agr * HID;

    const int rsw = (quad ^ ((l16 >> 1) & 3)) * 8;
    const int NT  = HID / 32;                  // 4

    const bf8_t* Bh0 = (const bf8_t*)Bhi;
    const bf8_t* Bl0 = (const bf8_t*)Blo;

    auto loadA = [&](int k0, float4& a0, float4& a1) {
        int gk = k0 + cl * 8;
        a0 = *(const float4*)(gH + gk);
        a1 = *(const float4*)(gH + gk + 4);
    };
    auto storeA = [&](int buf, int k0, float4 v0, float4 v1) {
        const int gk = k0 + cl * 8;
        float4 s0 = *(const float4*)&sSC[gk];
        float4 s1 = *(const float4*)&sSC[gk + 4];
        float4 t0 = *(const float4*)&sSC[HID + gk];
        float4 t1 = *(const float4*)&sSC[HID + gk + 4];
        float f[8];
        f[0] = fmaxf(v0.x * s0.x + t0.x, 0.f);
        f[1] = fmaxf(v0.y * s0.y + t0.y, 0.f);
        f[2] = fmaxf(v0.z * s0.z + t0.z, 0.f);
        f[3] = fmaxf(v0.w * s0.w + t0.w, 0.f);
        f[4] = fmaxf(v1.x * s1.x + t1.x, 0.f);
        f[5] = fmaxf(v1.y * s1.y + t1.y, 0.f);
        f[6] = fmaxf(v1.z * s1.z + t1.z, 0.f);
        f[7] = fmaxf(v1.w * s1.w + t1.w, 0.f);
        bf8_t h8, l8;
#pragma unroll
        for (int j = 0; j < 8; ++j) {
            unsigned short h = f2bf(f[j]);
            h8[j] = (short)h;
            l8[j] = (short)f2bf(f[j] - bf2f(h));
        }
        *(bf8_t*)&sAh[buf][ar * 32 + cpa * 8] = h8;
        *(bf8_t*)&sAl[buf][ar * 32 + cpa * 8] = l8;
    };
    auto loadB = [&](int t, bf8_t (&bh)[4], bf8_t (&bl)[4]) {
#pragma unroll
        for (int nt = 0; nt < 4; ++nt) {
            long bi = ((long)(wave * 4 + nt) * NT + t) * 64 + lane;
            bh[nt] = Bh0[bi];
            bl[nt] = Bl0[bi];
        }
    };

    // prologue: stage A step 0, prefetch B step 0
    bf8_t bhv[4], blv[4];
    {
        float4 a0, a1;
        loadA(0, a0, a1);
        loadB(0, bhv, blv);
        storeA(0, 0, a0, a1);
    }
    __syncthreads();

    int cur = 0;
#pragma unroll
    for (int t = 0; t < 4; ++t) {              // HID/32 = 4 steps
        float4 na0 = make_float4(0.f, 0.f, 0.f, 0.f);
        float4 na1 = make_float4(0.f, 0.f, 0.f, 0.f);
        bf8_t nbh[4], nbl[4];
        const bool more = (t < 3);
        if (more) {
            loadA((t + 1) * 32, na0, na1);
            loadB(t + 1, nbh, nbl);
        }

        bf8_t ah[4], al[4];
#pragma unroll
        for (int mt = 0; mt < 4; ++mt) {
            ah[mt] = *(const bf8_t*)&sAh[cur][(mt * 16 + l16) * 32 + rsw];
            al[mt] = *(const bf8_t*)&sAl[cur][(mt * 16 + l16) * 32 + rsw];
        }
#pragma unroll
        for (int nt = 0; nt < 4; ++nt)
#pragma unroll
            for (int mt = 0; mt < 4; ++mt)
                acc[mt][nt] = __builtin_amdgcn_mfma_f32_16x16x32_bf16(ah[mt], bhv[nt], acc[mt][nt], 0, 0, 0);
#pragma unroll
        for (int nt = 0; nt < 4; ++nt)
#pragma unroll
            for (int mt = 0; mt < 4; ++mt)
                acc[mt][nt] = __builtin_amdgcn_mfma_f32_16x16x32_bf16(al[mt], bhv[nt], acc[mt][nt], 0, 0, 0);
#pragma unroll
        for (int nt = 0; nt < 4; ++nt)
#pragma unroll
            for (int mt = 0; mt < 4; ++mt)
                acc[mt][nt] = __builtin_amdgcn_mfma_f32_16x16x32_bf16(ah[mt], blv[nt], acc[mt][nt], 0, 0, 0);

        if (more) {
            storeA(cur ^ 1, (t + 1) * 32, na0, na1);
#pragma unroll
            for (int nt = 0; nt < 4; ++nt) {
                bhv[nt] = nbh[nt];
                blv[nt] = nbl[nt];
            }
        }
        __syncthreads();
        cur ^= 1;
    }

    const bool left = (n0 < 128);
    if (left) {
        int ncol[4];
#pragma unroll
        for (int nt = 0; nt < 4; ++nt) ncol[nt] = n0 + nt * 16 + l16;
#pragma unroll
        for (int mt = 0; mt < 4; ++mt)
#pragma unroll
            for (int r = 0; r < 4; ++r) {
                long row = m0 + mt * 16 + quad * 4 + r;
                if (row < M) {
#pragma unroll
                    for (int nt = 0; nt < 4; ++nt)
                        C0[row * 128 + ncol[nt]] = f2bf(acc[mt][nt][r]);
                }
            }
    } else {
        float badd[4];
        int   ncol[4];
#pragma unroll
        for (int nt = 0; nt < 4; ++nt) {
            int ng = n0 + nt * 16 + l16 - 128;
            ncol[nt] = ng;
            badd[nt] = bias[ng];
        }
#pragma unroll
        for (int mt = 0; mt < 4; ++mt)
#pragma unroll
            for (int r = 0; r < 4; ++r) {
                long row = m0 + mt * 16 + quad * 4 + r;
                if (row < M) {
#pragma unroll
                    for (int nt = 0; nt < 4; ++nt)
                        C1[row * 128 + ncol[nt]] = acc[mt][nt][r] + badd[nt];
                }
            }
    }
}

// ---------------------------------------------------------------------------
// CSR gather (bf16 Pl) + BN-stat tail.
// 16-edge first flight (R6) + fused sum/sumsq tail in ONE LDS round (R9,
// bit-identical, 3 barriers -> 1).
// ---------------------------------------------------------------------------
__global__ __launch_bounds__(256) void gather_agg(const unsigned short* __restrict__ Pl,
                                                  const int* __restrict__ row_start,
                                                  const int* __restrict__ csr_src,
                                                  const float* __restrict__ invdeg,
                                                  float* __restrict__ out,
                                                  float* __restrict__ rep) {
    int slot = threadIdx.x >> 5;
    int lane = threadIdx.x & 31;
    int node = blockIdx.x * 8 + slot;          // grid exact: 6250*8 = 50000
    int beg = row_start[node];
    int end = row_start[node + 1];
    const unsigned short* base = Pl + lane * 4;
    float sx = 0.f, sy = 0.f, sz = 0.f, sw = 0.f;
    int j = beg;
    int deg = end - beg;

    // ---- first round: up to 16 edges, all loads in one flight ----
    if (deg > 0) {
        int n16 = (deg < 16) ? deg : 16;
        int idx[16];
#pragma unroll
        for (int u = 0; u < 16; ++u)
            idx[u] = csr_src[(u < n16) ? (j + u) : j];      // clamped: safe addr
        ushort4 v[16];
#pragma unroll
        for (int u = 0; u < 16; ++u)
            v[u] = *(const ushort4*)(base + (long)idx[u] * HID);
#pragma unroll
        for (int u = 0; u < 16; ++u) {
            float m = (u < n16) ? 1.f : 0.f;                // +0.f is exact
            sx += m * bf2f(v[u].x); sy += m * bf2f(v[u].y);
            sz += m * bf2f(v[u].z); sw += m * bf2f(v[u].w);
        }
        j += n16;
    }
    // ---- continuation for deg > 16 (rare) ----
    for (; j + 8 <= end; j += 8) {
        int idx[8];
#pragma unroll
        for (int u = 0; u < 8; ++u) idx[u] = csr_src[j + u];
        ushort4 v[8];
#pragma unroll
        for (int u = 0; u < 8; ++u) v[u] = *(const ushort4*)(base + (long)idx[u] * HID);
#pragma unroll
        for (int u = 0; u < 8; ++u) {
            sx += bf2f(v[u].x); sy += bf2f(v[u].y);
            sz += bf2f(v[u].z); sw += bf2f(v[u].w);
        }
    }
    if (j + 4 <= end) {
        int idx[4];
#pragma unroll
        for (int u = 0; u < 4; ++u) idx[u] = csr_src[j + u];
        ushort4 v[4];
#pragma unroll
        for (int u = 0; u < 4; ++u) v[u] = *(const ushort4*)(base + (long)idx[u] * HID);
#pragma unroll
        for (int u = 0; u < 4; ++u) {
            sx += bf2f(v[u].x); sy += bf2f(v[u].y);
            sz += bf2f(v[u].z); sw += bf2f(v[u].w);
        }
        j += 4;
    }
    for (; j < end; ++j) {
        int i0 = csr_src[j];
        ushort4 v0 = *(const ushort4*)(base + (long)i0 * HID);
        sx += bf2f(v0.x); sy += bf2f(v0.y); sz += bf2f(v0.z); sw += bf2f(v0.w);
    }
    float w = invdeg[node];
    float* o = out + (long)node * HID + lane * 4;
    float4 cur = *(float4*)o;
    cur.x += sx * w;
    cur.y += sy * w;
    cur.z += sz * w;
    cur.w += sw * w;
    *(float4*)o = cur;

    // ---- BN stats tail: one LDS round, sum + sumsq together ----
    __shared__ float red[8][HID];
    float* repb = rep + (blockIdx.x & (NREP - 1)) * 256;
    *(float4*)&red[slot][lane * 4] = make_float4(cur.x, cur.y, cur.z, cur.w);
    __syncthreads();
    if (threadIdx.x < HID) {
        float tsum = 0.f, tsq = 0.f;
#pragma unroll
        for (int s = 0; s < 8; ++s) {
            float v = red[s][threadIdx.x];
            tsum += v;
            tsq  += v * v;
        }
        atomicAdd(&repb[threadIdx.x], tsum);
        atomicAdd(&repb[HID + threadIdx.x], tsq);
    }
}

// ---------------------------------------------------------------------------
// fused BN+ReLU + mean-pool + head: one block/graph, 1024 thr. (R6 version)
// out = [logits(128x2) | hg(128x128)]
// ---------------------------------------------------------------------------
__global__ __launch_bounds__(1024) void poolhead_bn(const float* __restrict__ h,
                                                    const int* __restrict__ batch,
                                                    const float* __restrict__ rep,
                                                    const float* __restrict__ gamma,
                                                    const float* __restrict__ beta,
                                                    const float* __restrict__ Wc,
                                                    const float* __restrict__ bc,
                                                    float* __restrict__ out) {
    __shared__ float S[256];
    __shared__ float SC[256];
    int g = blockIdx.x;
    int t = threadIdx.x;
    int c = t & 127;
    int half = t >> 7;                 // 0..7
    if (t < 256) {
        float a = 0.f;
#pragma unroll
        for (int r = 0; r < NREP; ++r) a += rep[r * 256 + t];
        S[t] = a;
    }
    __shared__ int lo_sh, hi_sh;
    if (t == 0) {
        int lo = 0, hi = N_NODES;
        while (lo < hi) { int m = (lo + hi) >> 1; if (batch[m] < g) lo = m + 1; else hi = m; }
        lo_sh = lo;
        int lo2 = lo, hi2 = N_NODES;
        while (lo2 < hi2) { int m = (lo2 + hi2) >> 1; if (batch[m] < g + 1) lo2 = m + 1; else hi2 = m; }
        hi_sh = lo2;
    }
    __syncthreads();
    if (t < HID) {
        const float invn = 1.0f / (float)N_NODES;
        float mu  = S[t] * invn;
        float var = S[HID + t] * invn - mu * mu;
        float sc  = gamma[t] * rsqrtf(var + BN_EPS);
        SC[t]       = sc;
        SC[HID + t] = beta[t] - mu * sc;
    }
    __syncthreads();
    float bsc = SC[c], bsh = SC[HID + c];
    int lo = lo_sh, hi = hi_sh;
    float a0 = 0.f, a1 = 0.f, a2 = 0.f, a3 = 0.f;
    int r = lo + half;
    for (; r + 24 < hi; r += 32) {     // 4 independent loads in flight
        a0 += fmaxf(h[(long)(r +  0) * HID + c] * bsc + bsh, 0.f);
        a1 += fmaxf(h[(long)(r +  8) * HID + c] * bsc + bsh, 0.f);
        a2 += fmaxf(h[(long)(r + 16) * HID + c] * bsc + bsh, 0.f);
        a3 += fmaxf(h[(long)(r + 24) * HID + c] * bsc + bsh, 0.f);
    }
    for (; r < hi; r += 8) a0 += fmaxf(h[(long)r * HID + c] * bsc + bsh, 0.f);
    __shared__ float red[8][HID];
    red[half][c] = (a0 + a1) + (a2 + a3);
    __syncthreads();
    __shared__ float r0[HID], r1[HID];
    if (t < HID) {
        float inv = 1.0f / fmaxf((float)(hi - lo), 1.0f);
        float v = 0.f;
#pragma unroll
        for (int s = 0; s < 8; ++s) v += red[s][t];
        v *= inv;
        out[N_GRAPHS * N_CLASSES + g * HID + t] = v;   // hg
        r0[t] = v * Wc[t * 2 + 0];
        r1[t] = v * Wc[t * 2 + 1];
    }
    __syncthreads();
    if (t < 2) {
        const float* rr = t ? r1 : r0;
        float sum = bc[t];
        for (int i = 0; i < HID; ++i) sum += rr[i];
        out[g * 2 + t] = sum;
    }
}

// ---------------------------------------------------------------------------
// launch
// ---------------------------------------------------------------------------
extern "C" void kernel_launch(void* const* d_in, const int* in_sizes, int n_in,
                              void* d_out, int out_size, void* d_ws, size_t ws_size,
                              hipStream_t stream) {
    const float* x     = (const float*)d_in[0];
    const int*   ei    = (const int*)d_in[1];
    const int*   batch = (const int*)d_in[2];
    const float* W1l = (const float*)d_in[3];
    const float* W1r = (const float*)d_in[4];
    const float* b1  = (const float*)d_in[5];
    const float* g1  = (const float*)d_in[6];
    const float* be1 = (const float*)d_in[7];
    const float* W2l = (const float*)d_in[8];
    const float* W2r = (const float*)d_in[9];
    const float* b2  = (const float*)d_in[10];
    const float* g2  = (const float*)d_in[11];
    const float* be2 = (const float*)d_in[12];
    const float* W3l = (const float*)d_in[13];
    const float* W3r = (const float*)d_in[14];
    const float* b3  = (const float*)d_in[15];
    const float* g3  = (const float*)d_in[16];
    const float* be3 = (const float*)d_in[17];
    const float* Wc  = (const float*)d_in[18];
    const float* bc  = (const float*)d_in[19];

    const int* src = ei;
    const int* dst = ei + N_EDGES;

    float* ws = (float*)d_ws;
    const long FEAT = (long)N_NODES * HID;
    unsigned short* Pl16 = (unsigned short*)ws;      // FEAT ushorts
    float* buf1 = ws + FEAT;                         // layer 1&3 pre-BN h (fp32)
    float* buf2 = ws + 2 * FEAT;                     // layer 2 pre-BN h (fp32)
    int*   ideg      = (int*)(ws + 3 * FEAT);        // 50000
    int*   cursor    = ideg + N_NODES;               // 50000
    int*   bsum      = cursor + N_NODES;             // 128
    int*   bflag     = bsum + 128;                   // 128
    int*   row_start = bflag + 128;                  // 50001 (pad 50004)
    int*   csr_src   = row_start + N_NODES + 4;      // 600000
    float* invdeg    = (float*)(csr_src + N_EDGES);  // 50000
    float* reps      = invdeg + N_NODES;             // 3*32*256 = 24576
    unsigned short* B1h = (unsigned short*)(reps + 3 * NREP * 256);  // 256*320
    unsigned short* B1l = B1h + 256 * KP1;
    unsigned short* B2h = B1l + 256 * KP1;                           // 256*128
    unsigned short* B2l = B2h + 256 * HID;
    unsigned short* B3h = B2l + 256 * HID;
    unsigned short* B3l = B3h + 256 * HID;

    float* outp = (float*)d_out;

    const int gemm_grid   = (N_NODES + 63) / 64;     // 782
    const int gxf_grid    = GEMMX_BLOCKS + FILLB;    // 782 + 2344 = 3126
    const int gather_grid = N_NODES / 8;             // 6250 exact
    const int dp_grid     = DEGB + 320 + 128 + 128;  // 2920

    // --- zero scratch (2 memsets) ---
    hipMemsetAsync(ideg, 0, (2 * N_NODES + 256) * sizeof(int), stream);
    hipMemsetAsync(reps, 0, 3 * NREP * 256 * sizeof(float), stream);

    // --- degree + weight prep (merged), then scan ---
    deg_prepw<<<dp_grid, 256, 0, stream>>>(dst, ideg, W1l, W1r, W2l, W2r, W3l, W3r,
                                           B1h, B1l, B2h, B2l, B3h, B3l);
    scan_fused<<<NB, 256, 0, stream>>>(ideg, row_start, invdeg, bsum, bflag);

    // ---------------- layer 1 GEMM + CSR fill (merged dispatch) ----------------
    gemm_x_fill<<<gxf_grid, 256, 0, stream>>>(x, N_NODES, B1h, B1l, b1, Pl16, buf1,
                                              src, dst, row_start, cursor, csr_src);
    gather_agg<<<gather_grid, 256, 0, stream>>>(Pl16, row_start, csr_src, invdeg, buf1, reps);

    // ---------------- layer 2 (BN1 fused into A-staging) ----------------
    gemm_mfma_h<<<gemm_grid, 256, 0, stream>>>(buf1, N_NODES, reps, g1, be1,
                                               B2h, B2l, b2, Pl16, buf2);
    gather_agg<<<gather_grid, 256, 0, stream>>>(Pl16, row_start, csr_src, invdeg, buf2, reps + NREP * 256);

    // ---------------- layer 3 (BN2 fused into A-staging) ----------------
    gemm_mfma_h<<<gemm_grid, 256, 0, stream>>>(buf2, N_NODES, reps + NREP * 256, g2, be2,
                                               B3h, B3l, b3, Pl16, buf1);
    gather_agg<<<gather_grid, 256, 0, stream>>>(Pl16, row_start, csr_src, invdeg, buf1, reps + 2 * NREP * 256);

    // ---------------- fused BN3 + pool + head ----------------
    poolhead_bn<<<N_GRAPHS, 1024, 0, stream>>>(buf1, batch, reps + 2 * NREP * 256,
                                               g3, be3, Wc, bc, outp);
}